// Round 6
// baseline (2331.495 us; speedup 1.0000x reference)
//
#include <hip/hip_runtime.h>
#include <hip/hip_bf16.h>
#include <stdint.h>
#include <string.h>

// Problem constants (fixed by setup_inputs).
#define BB   16
#define NN   4096
#define NP   1024
#define KK   32
#define CP   64
#define CIN  67    // 3 + 64
#define H3   128

typedef __attribute__((ext_vector_type(8))) short short8;
typedef __attribute__((ext_vector_type(4))) float floatx4;
typedef __attribute__((ext_vector_type(2))) float f32x2;

// ---------- exact-rounding helpers (match numpy op-by-op; no fma contraction) ----------
__device__ __forceinline__ float sq3_exact(float x, float y, float z) {
#pragma clang fp contract(off)
    float a = x * x;
    float b = y * y;
    float c = z * z;
    return (a + b) + c;
}
__device__ __forceinline__ float dot3_exact(float ax, float ay, float az,
                                            float bx, float by, float bz) {
#pragma clang fp contract(off)
    float a = ax * bx;
    float b = ay * by;
    float c = az * bz;
    return (a + b) + c;
}
__device__ __forceinline__ float d2_exact(float sn, float sx, float dt) {
#pragma clang fp contract(off)
    return (sn + sx) - 2.0f * dt;
}
__device__ __forceinline__ uint32_t f32_sortable(float f) {
    uint32_t u = __float_as_uint(f);
    return u ^ ((uint32_t)((int32_t)u >> 31) | 0x80000000u);
}
__device__ __forceinline__ unsigned long long umax64(unsigned long long a, unsigned long long b) {
    return a > b ? a : b;
}
__device__ __forceinline__ uint32_t umax32(uint32_t a, uint32_t b) { return a > b ? a : b; }
__device__ __forceinline__ unsigned short bf16_bits(float f) {
    __hip_bfloat16 h = __float2bfloat16(f);
    unsigned short us;
    __builtin_memcpy(&us, &h, 2);
    return us;
}

// ---------- DPP wave64 reduces (VALU pipe; bound_ctrl=1 -> identity 0) ----------
template <int CTRL>
__device__ __forceinline__ uint32_t dpp_umax32_step(uint32_t k) {
    uint32_t o = (uint32_t)__builtin_amdgcn_update_dpp(0, (int)k, CTRL, 0xf, 0xf, true);
    return k > o ? k : o;
}
__device__ __forceinline__ uint32_t wave_umax32_dpp(uint32_t k) {
    k = dpp_umax32_step<0x111>(k);   // row_shr:1
    k = dpp_umax32_step<0x112>(k);   // row_shr:2
    k = dpp_umax32_step<0x114>(k);   // row_shr:4
    k = dpp_umax32_step<0x118>(k);   // row_shr:8
    k = dpp_umax32_step<0x142>(k);   // row_bcast:15
    k = dpp_umax32_step<0x143>(k);   // row_bcast:31
    return (uint32_t)__builtin_amdgcn_readlane((int)k, 63);
}
template <int CTRL>
__device__ __forceinline__ float dpp_fmax_step(float v) {
    int o = __builtin_amdgcn_update_dpp(0, __float_as_int(v), CTRL, 0xf, 0xf, true);
    return fmaxf(v, __int_as_float(o));   // folds to v_max_f32_dpp; 0.0 identity (v>=0)
}
__device__ __forceinline__ float wave_fmax_dpp(float v) {
    v = dpp_fmax_step<0x111>(v);
    v = dpp_fmax_step<0x112>(v);
    v = dpp_fmax_step<0x114>(v);
    v = dpp_fmax_step<0x118>(v);
    v = dpp_fmax_step<0x142>(v);
    v = dpp_fmax_step<0x143>(v);
    return __int_as_float(__builtin_amdgcn_readlane(__float_as_int(v), 63));
}

// ---------- kernel 1: transpose points (B,Cp,N) -> bf16 (B,N,Cp) ----------
__global__ void __launch_bounds__(256) transpose_pts(const float* __restrict__ pts,
                                                     __hip_bfloat16* __restrict__ ptsT) {
    __shared__ float tile[64][65];
    int b  = blockIdx.y;
    int n0 = blockIdx.x * 64;
    int tx = threadIdx.x & 63, ty = threadIdx.x >> 6;   // 64 x 4
    const float* src = pts + (size_t)b * CP * NN;
    for (int c = ty; c < 64; c += 4)
        tile[c][tx] = src[c * NN + n0 + tx];
    __syncthreads();
    __hip_bfloat16* dst = ptsT + ((size_t)b * NN + n0) * CP;
    for (int nn2 = ty; nn2 < 64; nn2 += 4)
        dst[nn2 * CP + tx] = __float2bfloat16(tile[tx][nn2]);
}

// ---------- kernel 1b: weights -> bf16, channel-reordered+padded ----------
__global__ void __launch_bounds__(256) prep_weights(const float* __restrict__ W1,
                                                    const float* __restrict__ W2,
                                                    const float* __restrict__ W3,
                                                    short* __restrict__ w1p,
                                                    short* __restrict__ w2p,
                                                    short* __restrict__ w3p) {
    int tid = blockIdx.x * 256 + threadIdx.x;
    int tot = gridDim.x * 256;
    for (int i = tid; i < 64 * 96; i += tot) {
        int o = i / 96, c = i % 96;
        float v = (c < 64) ? W1[o * CIN + 3 + c] : ((c < 67) ? W1[o * CIN + (c - 64)] : 0.0f);
        w1p[i] = (short)bf16_bits(v);
    }
    for (int i = tid; i < 64 * 64; i += tot)  w2p[i] = (short)bf16_bits(W2[i]);
    for (int i = tid; i < 128 * 64; i += tot) w3p[i] = (short)bf16_bits(W3[i]);
}

// ---------- kernel 2: FPS, one block per batch ----------
// 256 thr. Latency-chain-bound (R4: halving issue was neutral). This version
// attacks the chain: (a) tree-argmax over the 16 per-lane d's (serial 16-step
// max chain ~190cyc -> depth-4 tree ~35cyc, ties->left == smaller n);
// (b) v_max_f32_dpp fused wave reduce (nonneg, 0-identity).
#define FPS_T 256

__global__ void __launch_bounds__(FPS_T, 1) fps_kernel(const float* __restrict__ xyz,
                                                       float* __restrict__ newxyz) {
    __shared__ __attribute__((aligned(16))) float4 sxyz[NN];   // 64 KB
    __shared__ int farr[NP];
    __shared__ __attribute__((aligned(16))) unsigned long long kbuf[2][4];
    int b = blockIdx.x;
    int tid = threadIdx.x;
    const float* xb = xyz + (size_t)b * NN * 3;
    f32x2 px2[8], py2[8], pz2[8], dm2[8];
#pragma unroll
    for (int jj = 0; jj < 8; jj++) {
        int n0 = jj * 512 + tid;
        int n1 = n0 + 256;
        float x0 = xb[n0 * 3 + 0], y0 = xb[n0 * 3 + 1], z0 = xb[n0 * 3 + 2];
        float x1 = xb[n1 * 3 + 0], y1 = xb[n1 * 3 + 1], z1 = xb[n1 * 3 + 2];
        px2[jj] = (f32x2){x0, x1}; py2[jj] = (f32x2){y0, y1}; pz2[jj] = (f32x2){z0, z1};
        sxyz[n0] = make_float4(x0, y0, z0, 0.0f);
        sxyz[n1] = make_float4(x1, y1, z1, 0.0f);
        dm2[jj] = (f32x2){1e10f, 1e10f};              // matches 10000000000.0 init
    }
#pragma unroll
    for (int jj = 0; jj < 8; jj++) {                  // pin to VGPRs: no LDS remat
        asm volatile("" : "+v"(px2[jj]), "+v"(py2[jj]), "+v"(pz2[jj]));
    }
    if (tid == 0) farr[0] = 0;                        // cents[0] = 0
    __syncthreads();
    int far = 0;
    for (int t = 0; t < NP - 1; t++) {
        float4 c = sxyz[far];                         // broadcast ds_read_b128
        f32x2 ccx = (f32x2){c.x, c.x};
        f32x2 ccy = (f32x2){c.y, c.y};
        f32x2 ccz = (f32x2){c.z, c.z};
        float d[16];
#pragma unroll
        for (int jj = 0; jj < 8; jj++) {
            f32x2 dx, dy, dz, xx, yy, zz, s01, s;
            asm("v_pk_add_f32 %0, %1, %2 neg_lo:[0,1] neg_hi:[0,1]" : "=v"(dx) : "v"(px2[jj]), "v"(ccx));
            asm("v_pk_add_f32 %0, %1, %2 neg_lo:[0,1] neg_hi:[0,1]" : "=v"(dy) : "v"(py2[jj]), "v"(ccy));
            asm("v_pk_add_f32 %0, %1, %2 neg_lo:[0,1] neg_hi:[0,1]" : "=v"(dz) : "v"(pz2[jj]), "v"(ccz));
            asm("v_pk_mul_f32 %0, %1, %1" : "=v"(xx) : "v"(dx));
            asm("v_pk_mul_f32 %0, %1, %1" : "=v"(yy) : "v"(dy));
            asm("v_pk_mul_f32 %0, %1, %1" : "=v"(zz) : "v"(dz));
            asm("v_pk_add_f32 %0, %1, %2" : "=v"(s01) : "v"(xx), "v"(yy));
            asm("v_pk_add_f32 %0, %1, %2" : "=v"(s)   : "v"(s01), "v"(zz));
            float d0 = fminf(dm2[jj].x, s.x);
            float d1 = fminf(dm2[jj].y, s.y);
            dm2[jj].x = d0; dm2[jj].y = d1;
            d[2 * jj] = d0; d[2 * jj + 1] = d1;       // leaf l: n = l*256 + tid
        }
        // depth-4 tournament tree, ties -> left (smaller l -> smaller n)
        float tv[16]; int ti[16];
#pragma unroll
        for (int l = 0; l < 16; l++) { tv[l] = d[l]; ti[l] = l; }
#pragma unroll
        for (int stride = 1; stride < 16; stride <<= 1)
#pragma unroll
            for (int l = 0; l < 16; l += 2 * stride) {
                bool cgt = tv[l + stride] > tv[l];
                tv[l] = cgt ? tv[l + stride] : tv[l];
                ti[l] = cgt ? ti[l + stride] : ti[l];
            }
        float bv = tv[0];
        int   bn = ti[0] * 256 + tid;
        float mf = wave_fmax_dpp(bv);
        uint32_t mb = __float_as_uint(mf);
        unsigned long long mask = __ballot(__float_as_uint(bv) == mb);
        int n_sel;
        if (__popcll(mask) == 1) {
            n_sel = __builtin_amdgcn_readlane(bn, (int)(__ffsll((unsigned long long)mask) - 1));
        } else {                                      // rare: d-tie across lanes -> min n
            uint32_t cand = (__float_as_uint(bv) == mb) ? (uint32_t)bn : 0xFFFFFFFFu;
            n_sel = (int)~wave_umax32_dpp(~cand);
        }
        int par = t & 1;
        if ((tid & 63) == 0)
            kbuf[par][tid >> 6] = ((unsigned long long)mb << 32) | (unsigned)(NN - 1 - n_sel);
        __syncthreads();
        const ulonglong2* kp = (const ulonglong2*)kbuf[par];
        ulonglong2 k0 = kp[0], k1 = kp[1];
        unsigned long long mm = umax64(umax64(k0.x, k0.y), umax64(k1.x, k1.y));
        far = NN - 1 - (int)(unsigned)(mm & 0xFFFFFFFFull);
        if (tid == 0) farr[t + 1] = far;
    }
    __syncthreads();
    float* nxb = newxyz + (size_t)b * NP * 3;
    for (int t = tid; t < NP; t += FPS_T) {
        float4 p = sxyz[farr[t]];
        nxb[t * 3 + 0] = p.x;
        nxb[t * 3 + 1] = p.y;
        nxb[t * 3 + 2] = p.z;
    }
}

// ---------- kernel 3: exact kNN, ONE WAVE per (b,s) task ----------
// 64-thr blocks, no barriers. Lane owns 64 points (n = j*64+lane), keys
// ck = ~sortable(d2) (u32, max-extract == min-d2, identity 0) in LDS
// (dynamic index without scratch); 8 group-maxes cached in VGPRs. 32
// extraction rounds are paid once per task (R4 paid them per wave, 4x).
// Exact tie rule: value-ballot + min-n among tied (n-order == (j,lane) order).
__global__ void __launch_bounds__(64) knn_kernel(const float* __restrict__ xyz,
                                                 const float* __restrict__ newxyz,
                                                 unsigned short* __restrict__ knn_out) {
    __shared__ uint32_t keys[64 * 64];                // 16 KB: keys[j*64+lane]
    int s = blockIdx.x, b = blockIdx.y, lane = threadIdx.x;
    const float* c3 = newxyz + ((size_t)b * NP + s) * 3;
    float cx = c3[0], cy = c3[1], cz = c3[2];
    float sn = sq3_exact(cx, cy, cz);
    const float* xb = xyz + (size_t)b * NN * 3;
    uint32_t gv[8];
#pragma unroll
    for (int g = 0; g < 8; g++) gv[g] = 0;
#pragma unroll
    for (int j = 0; j < 64; j++) {
        int n = j * 64 + lane;
        float x = xb[n * 3 + 0], y = xb[n * 3 + 1], z = xb[n * 3 + 2];
        float sx = sq3_exact(x, y, z);
        float dt = dot3_exact(cx, cy, cz, x, y, z);
        float d2 = d2_exact(sn, sx, dt);
        uint32_t ck = ~f32_sortable(d2);
        keys[j * 64 + lane] = ck;
        gv[j >> 3] = umax32(gv[j >> 3], ck);
    }
    uint32_t best = 0;
#pragma unroll
    for (int g = 0; g < 8; g++) best = umax32(best, gv[g]);

    unsigned short* out = knn_out + ((size_t)b * NP + s) * KK;
    for (int r = 0; r < KK; r++) {
        uint32_t m = wave_umax32_dpp(best);
        unsigned long long mask = __ballot(best == m);
        bool cand = (best == m);
        uint32_t myn = 0xFFFFFFFFu;
        int gsel = 7, jl = 7;
        uint32_t grp[8];
        if (cand) {
            // smallest group whose max == m holds this lane's smallest j with key==m
#pragma unroll
            for (int g = 6; g >= 0; g--) if (gv[g] == m) gsel = g;
#pragma unroll
            for (int q = 0; q < 8; q++) grp[q] = keys[(gsel * 8 + q) * 64 + lane];
#pragma unroll
            for (int q = 6; q >= 0; q--) if (grp[q] == m) jl = q;
            myn = (uint32_t)((gsel * 8 + jl) * 64 + lane);
        }
        uint32_t n_sel;
        if (__popcll(mask) > 1) {                     // rare: d2-tie across lanes -> min n
            n_sel = ~wave_umax32_dpp(~myn);
        } else {
            n_sel = (uint32_t)__builtin_amdgcn_readlane((int)myn,
                        (int)(__ffsll((unsigned long long)mask) - 1));
        }
        if (lane == 0) out[r] = (unsigned short)n_sel;
        if (cand && myn == n_sel) {                   // owner: remove + rebuild
            keys[(gsel * 8 + jl) * 64 + lane] = 0;
#pragma unroll
            for (int q = 0; q < 8; q++) grp[q] = (q == jl) ? 0u : grp[q];
            uint32_t nv = 0;
#pragma unroll
            for (int q = 0; q < 8; q++) nv = umax32(nv, grp[q]);
#pragma unroll
            for (int g = 0; g < 8; g++) gv[g] = (g == gsel) ? nv : gv[g];
            best = 0;
#pragma unroll
            for (int g = 0; g < 8; g++) best = umax32(best, gv[g]);
        }
    }
}

// ---------- kernel 4: gather + 3-layer MLP via bf16 MFMA + maxpool ----------
__global__ void __launch_bounds__(256) mlp_mfma(const float* __restrict__ xyz,
                                                const __hip_bfloat16* __restrict__ ptsT,
                                                const unsigned short* __restrict__ knni,
                                                const short* __restrict__ w1p,
                                                const short* __restrict__ w2p,
                                                const short* __restrict__ w3p,
                                                const float* __restrict__ b1,
                                                const float* __restrict__ b2,
                                                const float* __restrict__ b3,
                                                float* __restrict__ out_np) {
    __shared__ __attribute__((aligned(16))) short lds[4 * 7680];   // 60 KB
    int tid  = threadIdx.x;
    int wave = tid >> 6, lane = tid & 63;
    int l15  = lane & 15, quad = lane >> 4;
    int gid  = blockIdx.x * 4 + wave;            // task = (b,s)
    int b    = gid >> 10, s = gid & (NP - 1);
    short* Gw  = lds + wave * 7680;              // 32 rows x 96
    short* h1w = Gw + 32 * 96;                   // 32 rows x 72
    short* h2w = h1w + 32 * 72;                  // 32 rows x 72

    float b1v[4], b2v[4], b3v[8];
#pragma unroll
    for (int i = 0; i < 4; i++) b1v[i] = b1[l15 + 16 * i];
#pragma unroll
    for (int i = 0; i < 4; i++) b2v[i] = b2[l15 + 16 * i];
#pragma unroll
    for (int i = 0; i < 8; i++) b3v[i] = b3[l15 + 16 * i];

    {   // gather: 32 neighbors -> G rows (2 lanes per row)
        int r = lane & 31, h = lane >> 5;
        int n = (int)knni[(size_t)gid * KK + r];
        const short8* prow = (const short8*)(ptsT + ((size_t)b * NN + n) * CP);
        short8 c0 = prow[h * 4 + 0], c1 = prow[h * 4 + 1];
        short8 c2 = prow[h * 4 + 2], c3 = prow[h * 4 + 3];
        short8* gdst = (short8*)&Gw[r * 96];
        gdst[h * 4 + 0] = c0; gdst[h * 4 + 1] = c1;
        gdst[h * 4 + 2] = c2; gdst[h * 4 + 3] = c3;
        short8 z8 = {0, 0, 0, 0, 0, 0, 0, 0};
        if (h == 0) {
            const float* xp = xyz + ((size_t)b * NN + n) * 3;
            short8 v = z8;
            v[0] = (short)bf16_bits(xp[0]);
            v[1] = (short)bf16_bits(xp[1]);
            v[2] = (short)bf16_bits(xp[2]);
            gdst[8] = v; gdst[9] = z8;
        } else {
            gdst[10] = z8; gdst[11] = z8;
        }
    }

    {   // layer 1: G(32x96) x W1p^T -> h1(32x64)
        floatx4 acc[2][4];
#pragma unroll
        for (int mt = 0; mt < 2; mt++)
#pragma unroll
            for (int nt = 0; nt < 4; nt++) acc[mt][nt] = (floatx4)0.0f;
#pragma unroll
        for (int kt = 0; kt < 3; kt++) {
            short8 a0 = *(const short8*)&Gw[(l15) * 96 + kt * 32 + quad * 8];
            short8 a1 = *(const short8*)&Gw[(l15 + 16) * 96 + kt * 32 + quad * 8];
#pragma unroll
            for (int nt = 0; nt < 4; nt++) {
                short8 bf = *(const short8*)&w1p[(l15 + 16 * nt) * 96 + kt * 32 + quad * 8];
                acc[0][nt] = __builtin_amdgcn_mfma_f32_16x16x32_bf16(a0, bf, acc[0][nt], 0, 0, 0);
                acc[1][nt] = __builtin_amdgcn_mfma_f32_16x16x32_bf16(a1, bf, acc[1][nt], 0, 0, 0);
            }
        }
#pragma unroll
        for (int mt = 0; mt < 2; mt++)
#pragma unroll
            for (int nt = 0; nt < 4; nt++)
#pragma unroll
                for (int r = 0; r < 4; r++) {
                    float v = fmaxf(acc[mt][nt][r] + b1v[nt], 0.0f);
                    h1w[(quad * 4 + r + 16 * mt) * 72 + l15 + 16 * nt] = (short)bf16_bits(v);
                }
    }

    {   // layer 2: h1(32x64) x W2^T -> h2(32x64)
        floatx4 acc[2][4];
#pragma unroll
        for (int mt = 0; mt < 2; mt++)
#pragma unroll
            for (int nt = 0; nt < 4; nt++) acc[mt][nt] = (floatx4)0.0f;
#pragma unroll
        for (int kt = 0; kt < 2; kt++) {
            short8 a0 = *(const short8*)&h1w[(l15) * 72 + kt * 32 + quad * 8];
            short8 a1 = *(const short8*)&h1w[(l15 + 16) * 72 + kt * 32 + quad * 8];
#pragma unroll
            for (int nt = 0; nt < 4; nt++) {
                short8 bf = *(const short8*)&w2p[(l15 + 16 * nt) * 64 + kt * 32 + quad * 8];
                acc[0][nt] = __builtin_amdgcn_mfma_f32_16x16x32_bf16(a0, bf, acc[0][nt], 0, 0, 0);
                acc[1][nt] = __builtin_amdgcn_mfma_f32_16x16x32_bf16(a1, bf, acc[1][nt], 0, 0, 0);
            }
        }
#pragma unroll
        for (int mt = 0; mt < 2; mt++)
#pragma unroll
            for (int nt = 0; nt < 4; nt++)
#pragma unroll
                for (int r = 0; r < 4; r++) {
                    float v = fmaxf(acc[mt][nt][r] + b2v[nt], 0.0f);
                    h2w[(quad * 4 + r + 16 * mt) * 72 + l15 + 16 * nt] = (short)bf16_bits(v);
                }
    }

    {   // layer 3: h2(32x64) x W3^T -> (32x128), fused maxpool over 32 pts
        floatx4 acc[2][8];
#pragma unroll
        for (int mt = 0; mt < 2; mt++)
#pragma unroll
            for (int nt = 0; nt < 8; nt++) acc[mt][nt] = (floatx4)0.0f;
#pragma unroll
        for (int kt = 0; kt < 2; kt++) {
            short8 a0 = *(const short8*)&h2w[(l15) * 72 + kt * 32 + quad * 8];
            short8 a1 = *(const short8*)&h2w[(l15 + 16) * 72 + kt * 32 + quad * 8];
#pragma unroll
            for (int nt = 0; nt < 8; nt++) {
                short8 bf = *(const short8*)&w3p[(l15 + 16 * nt) * 64 + kt * 32 + quad * 8];
                acc[0][nt] = __builtin_amdgcn_mfma_f32_16x16x32_bf16(a0, bf, acc[0][nt], 0, 0, 0);
                acc[1][nt] = __builtin_amdgcn_mfma_f32_16x16x32_bf16(a1, bf, acc[1][nt], 0, 0, 0);
            }
        }
#pragma unroll
        for (int nt = 0; nt < 8; nt++) {
            float m = acc[0][nt][0];
#pragma unroll
            for (int r = 1; r < 4; r++) m = fmaxf(m, acc[0][nt][r]);
#pragma unroll
            for (int r = 0; r < 4; r++) m = fmaxf(m, acc[1][nt][r]);
            m = fmaxf(m, __shfl_xor(m, 16));
            m = fmaxf(m, __shfl_xor(m, 32));
            m = fmaxf(m + b3v[nt], 0.0f);
            if (lane < 16)
                out_np[((size_t)b * H3 + l15 + 16 * nt) * NP + s] = m;
        }
    }
}

extern "C" void kernel_launch(void* const* d_in, const int* in_sizes, int n_in,
                              void* d_out, int out_size, void* d_ws, size_t ws_size,
                              hipStream_t stream) {
    (void)in_sizes; (void)n_in; (void)out_size; (void)ws_size;
    const float* xyz = (const float*)d_in[0];
    const float* pts = (const float*)d_in[1];
    const float* W1  = (const float*)d_in[2];
    const float* b1  = (const float*)d_in[3];
    const float* W2  = (const float*)d_in[4];
    const float* b2  = (const float*)d_in[5];
    const float* W3  = (const float*)d_in[6];
    const float* b3  = (const float*)d_in[7];

    float* out    = (float*)d_out;
    float* newxyz = out;                       // (B, NP, 3)
    float* newpts = out + (size_t)BB * NP * 3; // (B, 128, NP)

    char* ws = (char*)d_ws;
    __hip_bfloat16* ptsT = (__hip_bfloat16*)ws;                               // 8 MB
    unsigned short* knni = (unsigned short*)(ws + (size_t)BB * NN * CP * 2);  // 1 MB
    short* w1p = (short*)(ws + 9437184);
    short* w2p = w1p + 64 * 96;
    short* w3p = w2p + 64 * 64;

    transpose_pts<<<dim3(NN / 64, BB), 256, 0, stream>>>(pts, ptsT);
    prep_weights <<<64, 256, 0, stream>>>(W1, W2, W3, w1p, w2p, w3p);
    fps_kernel   <<<BB, FPS_T, 0, stream>>>(xyz, newxyz);
    knn_kernel   <<<dim3(NP, BB), 64, 0, stream>>>(xyz, newxyz, knni);
    mlp_mfma     <<<dim3(BB * NP / 4), 256, 0, stream>>>(xyz, ptsT, knni,
                                                         w1p, w2p, w3p, b1, b2, b3, newpts);
}

// Round 7
// 907.009 us; speedup vs baseline: 2.5705x; 2.5705x over previous
//
#include <hip/hip_runtime.h>
#include <hip/hip_bf16.h>
#include <stdint.h>
#include <string.h>

// Problem constants (fixed by setup_inputs).
#define BB   16
#define NN   4096
#define NP   1024
#define KK   32
#define CP   64
#define CIN  67    // 3 + 64
#define H3   128

typedef __attribute__((ext_vector_type(8))) short short8;
typedef __attribute__((ext_vector_type(4))) float floatx4;
typedef __attribute__((ext_vector_type(2))) float f32x2;

// ---------- exact-rounding helpers (match numpy op-by-op; no fma contraction) ----------
__device__ __forceinline__ float sq3_exact(float x, float y, float z) {
#pragma clang fp contract(off)
    float a = x * x;
    float b = y * y;
    float c = z * z;
    return (a + b) + c;
}
__device__ __forceinline__ float dot3_exact(float ax, float ay, float az,
                                            float bx, float by, float bz) {
#pragma clang fp contract(off)
    float a = ax * bx;
    float b = ay * by;
    float c = az * bz;
    return (a + b) + c;
}
__device__ __forceinline__ float d2_exact(float sn, float sx, float dt) {
#pragma clang fp contract(off)
    return (sn + sx) - 2.0f * dt;
}
__device__ __forceinline__ uint32_t f32_sortable(float f) {
    uint32_t u = __float_as_uint(f);
    return u ^ ((uint32_t)((int32_t)u >> 31) | 0x80000000u);
}
__device__ __forceinline__ unsigned long long umax64(unsigned long long a, unsigned long long b) {
    return a > b ? a : b;
}
__device__ __forceinline__ uint32_t umax32(uint32_t a, uint32_t b) { return a > b ? a : b; }
__device__ __forceinline__ unsigned short bf16_bits(float f) {
    __hip_bfloat16 h = __float2bfloat16(f);
    unsigned short us;
    __builtin_memcpy(&us, &h, 2);
    return us;
}

// ---------- DPP wave64 u32-max reduce (VALU pipe; bound_ctrl=1 -> identity 0) ----------
template <int CTRL>
__device__ __forceinline__ uint32_t dpp_umax32_step(uint32_t k) {
    uint32_t o = (uint32_t)__builtin_amdgcn_update_dpp(0, (int)k, CTRL, 0xf, 0xf, true);
    return k > o ? k : o;
}
__device__ __forceinline__ uint32_t wave_umax32_dpp(uint32_t k) {
    k = dpp_umax32_step<0x111>(k);   // row_shr:1
    k = dpp_umax32_step<0x112>(k);   // row_shr:2
    k = dpp_umax32_step<0x114>(k);   // row_shr:4
    k = dpp_umax32_step<0x118>(k);   // row_shr:8
    k = dpp_umax32_step<0x142>(k);   // row_bcast:15
    k = dpp_umax32_step<0x143>(k);   // row_bcast:31
    return (uint32_t)__builtin_amdgcn_readlane((int)k, 63);
}

// ---------- kernel 1: transpose points (B,Cp,N) -> bf16 (B,N,Cp) ----------
__global__ void __launch_bounds__(256) transpose_pts(const float* __restrict__ pts,
                                                     __hip_bfloat16* __restrict__ ptsT) {
    __shared__ float tile[64][65];
    int b  = blockIdx.y;
    int n0 = blockIdx.x * 64;
    int tx = threadIdx.x & 63, ty = threadIdx.x >> 6;   // 64 x 4
    const float* src = pts + (size_t)b * CP * NN;
    for (int c = ty; c < 64; c += 4)
        tile[c][tx] = src[c * NN + n0 + tx];
    __syncthreads();
    __hip_bfloat16* dst = ptsT + ((size_t)b * NN + n0) * CP;
    for (int nn2 = ty; nn2 < 64; nn2 += 4)
        dst[nn2 * CP + tx] = __float2bfloat16(tile[tx][nn2]);
}

// ---------- kernel 1b: weights -> bf16, channel-reordered+padded ----------
__global__ void __launch_bounds__(256) prep_weights(const float* __restrict__ W1,
                                                    const float* __restrict__ W2,
                                                    const float* __restrict__ W3,
                                                    short* __restrict__ w1p,
                                                    short* __restrict__ w2p,
                                                    short* __restrict__ w3p) {
    int tid = blockIdx.x * 256 + threadIdx.x;
    int tot = gridDim.x * 256;
    for (int i = tid; i < 64 * 96; i += tot) {
        int o = i / 96, c = i % 96;
        float v = (c < 64) ? W1[o * CIN + 3 + c] : ((c < 67) ? W1[o * CIN + (c - 64)] : 0.0f);
        w1p[i] = (short)bf16_bits(v);
    }
    for (int i = tid; i < 64 * 64; i += tot)  w2p[i] = (short)bf16_bits(W2[i]);
    for (int i = tid; i < 128 * 64; i += tot) w3p[i] = (short)bf16_bits(W3[i]);
}

// ---------- kernel 2: FPS, one block per batch (R5 version — known good) ----------
// 256 thr. R6's tree-argmax spilled to scratch (48 extra live regs at the 88-
// VGPR ceiling; scratch hits L2 so FETCH barely moved) -> 3.3x regression.
// Reverted: serial bv/bn chain, pk-f32 update, u32 DPP reduce + ballot.
#define FPS_T 256

__global__ void __launch_bounds__(FPS_T, 1) fps_kernel(const float* __restrict__ xyz,
                                                       float* __restrict__ newxyz) {
    __shared__ __attribute__((aligned(16))) float4 sxyz[NN];   // 64 KB
    __shared__ int farr[NP];
    __shared__ __attribute__((aligned(16))) unsigned long long kbuf[2][4];
    int b = blockIdx.x;
    int tid = threadIdx.x;
    const float* xb = xyz + (size_t)b * NN * 3;
    f32x2 px2[8], py2[8], pz2[8], dm2[8];
#pragma unroll
    for (int jj = 0; jj < 8; jj++) {
        int n0 = jj * 512 + tid;
        int n1 = n0 + 256;
        float x0 = xb[n0 * 3 + 0], y0 = xb[n0 * 3 + 1], z0 = xb[n0 * 3 + 2];
        float x1 = xb[n1 * 3 + 0], y1 = xb[n1 * 3 + 1], z1 = xb[n1 * 3 + 2];
        px2[jj] = (f32x2){x0, x1}; py2[jj] = (f32x2){y0, y1}; pz2[jj] = (f32x2){z0, z1};
        sxyz[n0] = make_float4(x0, y0, z0, 0.0f);
        sxyz[n1] = make_float4(x1, y1, z1, 0.0f);
        dm2[jj] = (f32x2){1e10f, 1e10f};              // matches 10000000000.0 init
    }
#pragma unroll
    for (int jj = 0; jj < 8; jj++) {                  // pin to VGPRs: no LDS remat
        asm volatile("" : "+v"(px2[jj]), "+v"(py2[jj]), "+v"(pz2[jj]));
    }
    if (tid == 0) farr[0] = 0;                        // cents[0] = 0
    __syncthreads();
    int far = 0;
    for (int t = 0; t < NP - 1; t++) {
        float4 c = sxyz[far];                         // broadcast ds_read_b128
        f32x2 ccx = (f32x2){c.x, c.x};
        f32x2 ccy = (f32x2){c.y, c.y};
        f32x2 ccz = (f32x2){c.z, c.z};
        float bv = -1.0f; int bn = 0;
#pragma unroll
        for (int jj = 0; jj < 8; jj++) {
            f32x2 dx, dy, dz, xx, yy, zz, s01, s;
            asm("v_pk_add_f32 %0, %1, %2 neg_lo:[0,1] neg_hi:[0,1]" : "=v"(dx) : "v"(px2[jj]), "v"(ccx));
            asm("v_pk_add_f32 %0, %1, %2 neg_lo:[0,1] neg_hi:[0,1]" : "=v"(dy) : "v"(py2[jj]), "v"(ccy));
            asm("v_pk_add_f32 %0, %1, %2 neg_lo:[0,1] neg_hi:[0,1]" : "=v"(dz) : "v"(pz2[jj]), "v"(ccz));
            asm("v_pk_mul_f32 %0, %1, %1" : "=v"(xx) : "v"(dx));
            asm("v_pk_mul_f32 %0, %1, %1" : "=v"(yy) : "v"(dy));
            asm("v_pk_mul_f32 %0, %1, %1" : "=v"(zz) : "v"(dz));
            asm("v_pk_add_f32 %0, %1, %2" : "=v"(s01) : "v"(xx), "v"(yy));
            asm("v_pk_add_f32 %0, %1, %2" : "=v"(s)   : "v"(s01), "v"(zz));
            float d0 = fminf(dm2[jj].x, s.x);
            dm2[jj].x = d0;
            bn = (d0 > bv) ? (jj * 512 + tid) : bn;   // ascending n scan: ties -> smaller n
            bv = fmaxf(bv, d0);
            float d1 = fminf(dm2[jj].y, s.y);
            dm2[jj].y = d1;
            bn = (d1 > bv) ? (jj * 512 + 256 + tid) : bn;
            bv = fmaxf(bv, d1);
        }
        uint32_t bvb = __float_as_uint(bv);           // bv >= 0: bits order-isomorphic
        uint32_t m = wave_umax32_dpp(bvb);
        unsigned long long mask = __ballot(bvb == m);
        int n_sel;
        if (__popcll(mask) == 1) {
            n_sel = __builtin_amdgcn_readlane(bn, (int)(__ffsll((unsigned long long)mask) - 1));
        } else {                                      // rare: d-tie across lanes -> min n
            uint32_t cand = (bvb == m) ? (uint32_t)bn : 0xFFFFFFFFu;
            n_sel = (int)~wave_umax32_dpp(~cand);
        }
        int par = t & 1;
        if ((tid & 63) == 0)
            kbuf[par][tid >> 6] = ((unsigned long long)m << 32) | (unsigned)(NN - 1 - n_sel);
        __syncthreads();
        const ulonglong2* kp = (const ulonglong2*)kbuf[par];
        ulonglong2 k0 = kp[0], k1 = kp[1];
        unsigned long long mm = umax64(umax64(k0.x, k0.y), umax64(k1.x, k1.y));
        far = NN - 1 - (int)(unsigned)(mm & 0xFFFFFFFFull);
        if (tid == 0) farr[t + 1] = far;
    }
    __syncthreads();
    float* nxb = newxyz + (size_t)b * NP * 3;
    for (int t = tid; t < NP; t += FPS_T) {
        float4 p = sxyz[farr[t]];
        nxb[t * 3 + 0] = p.x;
        nxb[t * 3 + 1] = p.y;
        nxb[t * 3 + 2] = p.z;
    }
}

// ---------- kernel 3: exact kNN, ONE WAVE per (b,s) task (R6 version — good) ----------
__global__ void __launch_bounds__(64) knn_kernel(const float* __restrict__ xyz,
                                                 const float* __restrict__ newxyz,
                                                 unsigned short* __restrict__ knn_out) {
    __shared__ uint32_t keys[64 * 64];                // 16 KB: keys[j*64+lane]
    int s = blockIdx.x, b = blockIdx.y, lane = threadIdx.x;
    const float* c3 = newxyz + ((size_t)b * NP + s) * 3;
    float cx = c3[0], cy = c3[1], cz = c3[2];
    float sn = sq3_exact(cx, cy, cz);
    const float* xb = xyz + (size_t)b * NN * 3;
    uint32_t gv[8];
#pragma unroll
    for (int g = 0; g < 8; g++) gv[g] = 0;
#pragma unroll
    for (int j = 0; j < 64; j++) {
        int n = j * 64 + lane;
        float x = xb[n * 3 + 0], y = xb[n * 3 + 1], z = xb[n * 3 + 2];
        float sx = sq3_exact(x, y, z);
        float dt = dot3_exact(cx, cy, cz, x, y, z);
        float d2 = d2_exact(sn, sx, dt);
        uint32_t ck = ~f32_sortable(d2);
        keys[j * 64 + lane] = ck;
        gv[j >> 3] = umax32(gv[j >> 3], ck);
    }
    uint32_t best = 0;
#pragma unroll
    for (int g = 0; g < 8; g++) best = umax32(best, gv[g]);

    unsigned short* out = knn_out + ((size_t)b * NP + s) * KK;
    for (int r = 0; r < KK; r++) {
        uint32_t m = wave_umax32_dpp(best);
        unsigned long long mask = __ballot(best == m);
        bool cand = (best == m);
        uint32_t myn = 0xFFFFFFFFu;
        int gsel = 7, jl = 7;
        uint32_t grp[8];
        if (cand) {
#pragma unroll
            for (int g = 6; g >= 0; g--) if (gv[g] == m) gsel = g;
#pragma unroll
            for (int q = 0; q < 8; q++) grp[q] = keys[(gsel * 8 + q) * 64 + lane];
#pragma unroll
            for (int q = 6; q >= 0; q--) if (grp[q] == m) jl = q;
            myn = (uint32_t)((gsel * 8 + jl) * 64 + lane);
        }
        uint32_t n_sel;
        if (__popcll(mask) > 1) {                     // rare: d2-tie across lanes -> min n
            n_sel = ~wave_umax32_dpp(~myn);
        } else {
            n_sel = (uint32_t)__builtin_amdgcn_readlane((int)myn,
                        (int)(__ffsll((unsigned long long)mask) - 1));
        }
        if (lane == 0) out[r] = (unsigned short)n_sel;
        if (cand && myn == n_sel) {                   // owner: remove + rebuild
            keys[(gsel * 8 + jl) * 64 + lane] = 0;
#pragma unroll
            for (int q = 0; q < 8; q++) grp[q] = (q == jl) ? 0u : grp[q];
            uint32_t nv = 0;
#pragma unroll
            for (int q = 0; q < 8; q++) nv = umax32(nv, grp[q]);
#pragma unroll
            for (int g = 0; g < 8; g++) gv[g] = (g == gsel) ? nv : gv[g];
            best = 0;
#pragma unroll
            for (int g = 0; g < 8; g++) best = umax32(best, gv[g]);
        }
    }
}

// ---------- kernel 4: gather + 3-layer MLP via bf16 MFMA + maxpool ----------
// One (b,s) task per wave, wave-private LDS, no barriers. LDS buffers ALIASED
// (G dead after layer 1 -> h2 overlays G): 10.5 KB/wave, 42 KB/block ->
// 3 blocks/CU (was 60 KB -> 2). Within-wave DS ordering is guaranteed by
// data deps + in-order lgkmcnt retirement; no barrier needed.
#define MLP_WSZ (32 * 96 + 32 * 72)   // 5376 shorts/wave

__global__ void __launch_bounds__(256) mlp_mfma(const float* __restrict__ xyz,
                                                const __hip_bfloat16* __restrict__ ptsT,
                                                const unsigned short* __restrict__ knni,
                                                const short* __restrict__ w1p,
                                                const short* __restrict__ w2p,
                                                const short* __restrict__ w3p,
                                                const float* __restrict__ b1,
                                                const float* __restrict__ b2,
                                                const float* __restrict__ b3,
                                                float* __restrict__ out_np) {
    __shared__ __attribute__((aligned(16))) short lds[4 * MLP_WSZ];   // 42 KB
    int tid  = threadIdx.x;
    int wave = tid >> 6, lane = tid & 63;
    int l15  = lane & 15, quad = lane >> 4;
    int gid  = blockIdx.x * 4 + wave;            // task = (b,s)
    int b    = gid >> 10, s = gid & (NP - 1);
    short* Gw  = lds + wave * MLP_WSZ;           // 32 rows x 96 (dead after layer 1)
    short* h1w = Gw + 32 * 96;                   // 32 rows x 72
    short* h2w = Gw;                             // aliases G (32 rows x 72)

    float b1v[4], b2v[4], b3v[8];
#pragma unroll
    for (int i = 0; i < 4; i++) b1v[i] = b1[l15 + 16 * i];
#pragma unroll
    for (int i = 0; i < 4; i++) b2v[i] = b2[l15 + 16 * i];
#pragma unroll
    for (int i = 0; i < 8; i++) b3v[i] = b3[l15 + 16 * i];

    {   // gather: 32 neighbors -> G rows (2 lanes per row)
        int r = lane & 31, h = lane >> 5;
        int n = (int)knni[(size_t)gid * KK + r];
        const short8* prow = (const short8*)(ptsT + ((size_t)b * NN + n) * CP);
        short8 c0 = prow[h * 4 + 0], c1 = prow[h * 4 + 1];
        short8 c2 = prow[h * 4 + 2], c3 = prow[h * 4 + 3];
        short8* gdst = (short8*)&Gw[r * 96];
        gdst[h * 4 + 0] = c0; gdst[h * 4 + 1] = c1;
        gdst[h * 4 + 2] = c2; gdst[h * 4 + 3] = c3;
        short8 z8 = {0, 0, 0, 0, 0, 0, 0, 0};
        if (h == 0) {
            const float* xp = xyz + ((size_t)b * NN + n) * 3;
            short8 v = z8;
            v[0] = (short)bf16_bits(xp[0]);
            v[1] = (short)bf16_bits(xp[1]);
            v[2] = (short)bf16_bits(xp[2]);
            gdst[8] = v; gdst[9] = z8;
        } else {
            gdst[10] = z8; gdst[11] = z8;
        }
    }

    {   // layer 1: G(32x96) x W1p^T -> h1(32x64)
        floatx4 acc[2][4];
#pragma unroll
        for (int mt = 0; mt < 2; mt++)
#pragma unroll
            for (int nt = 0; nt < 4; nt++) acc[mt][nt] = (floatx4)0.0f;
#pragma unroll
        for (int kt = 0; kt < 3; kt++) {
            short8 a0 = *(const short8*)&Gw[(l15) * 96 + kt * 32 + quad * 8];
            short8 a1 = *(const short8*)&Gw[(l15 + 16) * 96 + kt * 32 + quad * 8];
#pragma unroll
            for (int nt = 0; nt < 4; nt++) {
                short8 bf = *(const short8*)&w1p[(l15 + 16 * nt) * 96 + kt * 32 + quad * 8];
                acc[0][nt] = __builtin_amdgcn_mfma_f32_16x16x32_bf16(a0, bf, acc[0][nt], 0, 0, 0);
                acc[1][nt] = __builtin_amdgcn_mfma_f32_16x16x32_bf16(a1, bf, acc[1][nt], 0, 0, 0);
            }
        }
#pragma unroll
        for (int mt = 0; mt < 2; mt++)
#pragma unroll
            for (int nt = 0; nt < 4; nt++)
#pragma unroll
                for (int r = 0; r < 4; r++) {
                    float v = fmaxf(acc[mt][nt][r] + b1v[nt], 0.0f);
                    h1w[(quad * 4 + r + 16 * mt) * 72 + l15 + 16 * nt] = (short)bf16_bits(v);
                }
    }

    {   // layer 2: h1(32x64) x W2^T -> h2(32x64)  (h2 overlays dead G)
        floatx4 acc[2][4];
#pragma unroll
        for (int mt = 0; mt < 2; mt++)
#pragma unroll
            for (int nt = 0; nt < 4; nt++) acc[mt][nt] = (floatx4)0.0f;
#pragma unroll
        for (int kt = 0; kt < 2; kt++) {
            short8 a0 = *(const short8*)&h1w[(l15) * 72 + kt * 32 + quad * 8];
            short8 a1 = *(const short8*)&h1w[(l15 + 16) * 72 + kt * 32 + quad * 8];
#pragma unroll
            for (int nt = 0; nt < 4; nt++) {
                short8 bf = *(const short8*)&w2p[(l15 + 16 * nt) * 64 + kt * 32 + quad * 8];
                acc[0][nt] = __builtin_amdgcn_mfma_f32_16x16x32_bf16(a0, bf, acc[0][nt], 0, 0, 0);
                acc[1][nt] = __builtin_amdgcn_mfma_f32_16x16x32_bf16(a1, bf, acc[1][nt], 0, 0, 0);
            }
        }
#pragma unroll
        for (int mt = 0; mt < 2; mt++)
#pragma unroll
            for (int nt = 0; nt < 4; nt++)
#pragma unroll
                for (int r = 0; r < 4; r++) {
                    float v = fmaxf(acc[mt][nt][r] + b2v[nt], 0.0f);
                    h2w[(quad * 4 + r + 16 * mt) * 72 + l15 + 16 * nt] = (short)bf16_bits(v);
                }
    }

    {   // layer 3: h2(32x64) x W3^T -> (32x128), fused maxpool over 32 pts
        floatx4 acc[2][8];
#pragma unroll
        for (int mt = 0; mt < 2; mt++)
#pragma unroll
            for (int nt = 0; nt < 8; nt++) acc[mt][nt] = (floatx4)0.0f;
#pragma unroll
        for (int kt = 0; kt < 2; kt++) {
            short8 a0 = *(const short8*)&h2w[(l15) * 72 + kt * 32 + quad * 8];
            short8 a1 = *(const short8*)&h2w[(l15 + 16) * 72 + kt * 32 + quad * 8];
#pragma unroll
            for (int nt = 0; nt < 8; nt++) {
                short8 bf = *(const short8*)&w3p[(l15 + 16 * nt) * 64 + kt * 32 + quad * 8];
                acc[0][nt] = __builtin_amdgcn_mfma_f32_16x16x32_bf16(a0, bf, acc[0][nt], 0, 0, 0);
                acc[1][nt] = __builtin_amdgcn_mfma_f32_16x16x32_bf16(a1, bf, acc[1][nt], 0, 0, 0);
            }
        }
#pragma unroll
        for (int nt = 0; nt < 8; nt++) {
            float m = acc[0][nt][0];
#pragma unroll
            for (int r = 1; r < 4; r++) m = fmaxf(m, acc[0][nt][r]);
#pragma unroll
            for (int r = 0; r < 4; r++) m = fmaxf(m, acc[1][nt][r]);
            m = fmaxf(m, __shfl_xor(m, 16));
            m = fmaxf(m, __shfl_xor(m, 32));
            m = fmaxf(m + b3v[nt], 0.0f);
            if (lane < 16)
                out_np[((size_t)b * H3 + l15 + 16 * nt) * NP + s] = m;
        }
    }
}

extern "C" void kernel_launch(void* const* d_in, const int* in_sizes, int n_in,
                              void* d_out, int out_size, void* d_ws, size_t ws_size,
                              hipStream_t stream) {
    (void)in_sizes; (void)n_in; (void)out_size; (void)ws_size;
    const float* xyz = (const float*)d_in[0];
    const float* pts = (const float*)d_in[1];
    const float* W1  = (const float*)d_in[2];
    const float* b1  = (const float*)d_in[3];
    const float* W2  = (const float*)d_in[4];
    const float* b2  = (const float*)d_in[5];
    const float* W3  = (const float*)d_in[6];
    const float* b3  = (const float*)d_in[7];

    float* out    = (float*)d_out;
    float* newxyz = out;                       // (B, NP, 3)
    float* newpts = out + (size_t)BB * NP * 3; // (B, 128, NP)

    char* ws = (char*)d_ws;
    __hip_bfloat16* ptsT = (__hip_bfloat16*)ws;                               // 8 MB
    unsigned short* knni = (unsigned short*)(ws + (size_t)BB * NN * CP * 2);  // 1 MB
    short* w1p = (short*)(ws + 9437184);
    short* w2p = w1p + 64 * 96;
    short* w3p = w2p + 64 * 64;

    transpose_pts<<<dim3(NN / 64, BB), 256, 0, stream>>>(pts, ptsT);
    prep_weights <<<64, 256, 0, stream>>>(W1, W2, W3, w1p, w2p, w3p);
    fps_kernel   <<<BB, FPS_T, 0, stream>>>(xyz, newxyz);
    knn_kernel   <<<dim3(NP, BB), 64, 0, stream>>>(xyz, newxyz, knni);
    mlp_mfma     <<<dim3(BB * NP / 4), 256, 0, stream>>>(xyz, ptsT, knni,
                                                         w1p, w2p, w3p, b1, b2, b3, newpts);
}

// Round 9
// 762.154 us; speedup vs baseline: 3.0591x; 1.1901x over previous
//
#include <hip/hip_runtime.h>
#include <hip/hip_bf16.h>
#include <stdint.h>
#include <string.h>

// Problem constants (fixed by setup_inputs).
#define BB   16
#define NN   4096
#define NP   1024
#define KK   32
#define CP   64
#define CIN  67    // 3 + 64
#define H3   128

#define FPS_T   256
#define NWORKB  496                 // worker blocks
#define NGRID   (BB + NWORKB)       // 512 = 256 CUs x 2 blocks -> all co-resident
#define NWAVES  (NWORKB * 4)        // 1984 worker waves for 16384 tasks

typedef __attribute__((ext_vector_type(8))) short short8;
typedef __attribute__((ext_vector_type(4))) float floatx4;
typedef __attribute__((ext_vector_type(2))) float f32x2;

// ---------- exact-rounding helpers (match numpy op-by-op; no fma contraction) ----------
__device__ __forceinline__ float sq3_exact(float x, float y, float z) {
#pragma clang fp contract(off)
    float a = x * x;
    float b = y * y;
    float c = z * z;
    return (a + b) + c;
}
__device__ __forceinline__ float dot3_exact(float ax, float ay, float az,
                                            float bx, float by, float bz) {
#pragma clang fp contract(off)
    float a = ax * bx;
    float b = ay * by;
    float c = az * bz;
    return (a + b) + c;
}
__device__ __forceinline__ float d2_exact(float sn, float sx, float dt) {
#pragma clang fp contract(off)
    return (sn + sx) - 2.0f * dt;
}
__device__ __forceinline__ uint32_t f32_sortable(float f) {
    uint32_t u = __float_as_uint(f);
    return u ^ ((uint32_t)((int32_t)u >> 31) | 0x80000000u);
}
__device__ __forceinline__ unsigned long long umax64(unsigned long long a, unsigned long long b) {
    return a > b ? a : b;
}
__device__ __forceinline__ uint32_t umax32(uint32_t a, uint32_t b) { return a > b ? a : b; }
__device__ __forceinline__ unsigned short bf16_bits(float f) {
    __hip_bfloat16 h = __float2bfloat16(f);
    unsigned short us;
    __builtin_memcpy(&us, &h, 2);
    return us;
}

// ---------- DPP wave64 u32-max reduce (VALU pipe; bound_ctrl=1 -> identity 0) ----------
template <int CTRL>
__device__ __forceinline__ uint32_t dpp_umax32_step(uint32_t k) {
    uint32_t o = (uint32_t)__builtin_amdgcn_update_dpp(0, (int)k, CTRL, 0xf, 0xf, true);
    return k > o ? k : o;
}
__device__ __forceinline__ uint32_t wave_umax32_dpp(uint32_t k) {
    k = dpp_umax32_step<0x111>(k);   // row_shr:1
    k = dpp_umax32_step<0x112>(k);   // row_shr:2
    k = dpp_umax32_step<0x114>(k);   // row_shr:4
    k = dpp_umax32_step<0x118>(k);   // row_shr:8
    k = dpp_umax32_step<0x142>(k);   // row_bcast:15
    k = dpp_umax32_step<0x143>(k);   // row_bcast:31
    return (uint32_t)__builtin_amdgcn_readlane((int)k, 63);
}

// ---------- kernel 1: transpose points (B,Cp,N) -> bf16 (B,N,Cp) ----------
__global__ void __launch_bounds__(256) transpose_pts(const float* __restrict__ pts,
                                                     __hip_bfloat16* __restrict__ ptsT) {
    __shared__ float tile[64][65];
    int b  = blockIdx.y;
    int n0 = blockIdx.x * 64;
    int tx = threadIdx.x & 63, ty = threadIdx.x >> 6;   // 64 x 4
    const float* src = pts + (size_t)b * CP * NN;
    for (int c = ty; c < 64; c += 4)
        tile[c][tx] = src[c * NN + n0 + tx];
    __syncthreads();
    __hip_bfloat16* dst = ptsT + ((size_t)b * NN + n0) * CP;
    for (int nn2 = ty; nn2 < 64; nn2 += 4)
        dst[nn2 * CP + tx] = __float2bfloat16(tile[tx][nn2]);
}

// ---------- kernel 1b: weights -> bf16 + ZERO the centroid-publish flags ----------
// centpub zeroing here fixes R8's failure: the harness only re-poisons d_ws
// before TIMED launches; the first correctness call can see garbage where a
// stale hi16==1 bit made workers consume a bogus centroid. prep_weights runs
// before fused_kernel on the stream every launch, so the zeroing is ordered.
__global__ void __launch_bounds__(256) prep_weights(const float* __restrict__ W1,
                                                    const float* __restrict__ W2,
                                                    const float* __restrict__ W3,
                                                    short* __restrict__ w1p,
                                                    short* __restrict__ w2p,
                                                    short* __restrict__ w3p,
                                                    uint32_t* __restrict__ centpub) {
    int tid = blockIdx.x * 256 + threadIdx.x;
    int tot = gridDim.x * 256;
    for (int i = tid; i < BB * NP; i += tot) centpub[i] = 0u;   // not-ready
    for (int i = tid; i < 64 * 96; i += tot) {
        int o = i / 96, c = i % 96;
        float v = (c < 64) ? W1[o * CIN + 3 + c] : ((c < 67) ? W1[o * CIN + (c - 64)] : 0.0f);
        w1p[i] = (short)bf16_bits(v);
    }
    for (int i = tid; i < 64 * 64; i += tot)  w2p[i] = (short)bf16_bits(W2[i]);
    for (int i = tid; i < 128 * 64; i += tot) w3p[i] = (short)bf16_bits(W3[i]);
}

// ---------- fused kernel: 16 FPS producer blocks + 496 knn+mlp worker blocks ----------
// Safety: __launch_bounds__(256,2) + 69.7KB LDS => exactly 2 blocks/CU => all 512
// blocks co-resident regardless of dispatch order => spin-wait cannot deadlock.
// Protocol: fps publishes centroid s as ONE relaxed agent-scope atomic u32
// (0x10000 | far). Payload is self-contained (consumer reads coords from the
// immutable xyz input), so no fences/ordering needed. centpub pre-zeroed by
// prep_weights => hi16==1 is an unambiguous ready flag on every launch.
__global__ void __launch_bounds__(256, 2)
fused_kernel(const float* __restrict__ xyz,
             const __hip_bfloat16* __restrict__ ptsT,
             const short* __restrict__ w1p,
             const short* __restrict__ w2p,
             const short* __restrict__ w3p,
             const float* __restrict__ b1,
             const float* __restrict__ b2,
             const float* __restrict__ b3,
             uint32_t* __restrict__ centpub,
             float* __restrict__ out) {
    __shared__ __attribute__((aligned(16))) char smem[69696];
    int tid = threadIdx.x;

    if (blockIdx.x < BB) {
        // ================= FPS producer (R7 body + per-iter publish) =================
        asm volatile("s_setprio 3");            // win SIMD issue vs co-resident workers
        float4* sxyz = (float4*)smem;                                   // 64 KB
        int*    farr = (int*)(smem + 65536);                            // 4 KB
        unsigned long long* kbufp = (unsigned long long*)(smem + 69632);// 64 B
        int b = blockIdx.x;
        uint32_t* pub = centpub + b * NP;
        const float* xb = xyz + (size_t)b * NN * 3;
        if (tid == 0)
            __hip_atomic_store(&pub[0], 0x10000u, __ATOMIC_RELAXED, __HIP_MEMORY_SCOPE_AGENT);
        f32x2 px2[8], py2[8], pz2[8], dm2[8];
#pragma unroll
        for (int jj = 0; jj < 8; jj++) {
            int n0 = jj * 512 + tid;
            int n1 = n0 + 256;
            float x0 = xb[n0 * 3 + 0], y0 = xb[n0 * 3 + 1], z0 = xb[n0 * 3 + 2];
            float x1 = xb[n1 * 3 + 0], y1 = xb[n1 * 3 + 1], z1 = xb[n1 * 3 + 2];
            px2[jj] = (f32x2){x0, x1}; py2[jj] = (f32x2){y0, y1}; pz2[jj] = (f32x2){z0, z1};
            sxyz[n0] = make_float4(x0, y0, z0, 0.0f);
            sxyz[n1] = make_float4(x1, y1, z1, 0.0f);
            dm2[jj] = (f32x2){1e10f, 1e10f};              // matches 10000000000.0 init
        }
#pragma unroll
        for (int jj = 0; jj < 8; jj++) {                  // pin to VGPRs: no LDS remat
            asm volatile("" : "+v"(px2[jj]), "+v"(py2[jj]), "+v"(pz2[jj]));
        }
        if (tid == 0) farr[0] = 0;                        // cents[0] = 0
        __syncthreads();
        int far = 0;
        for (int t = 0; t < NP - 1; t++) {
            float4 c = sxyz[far];                         // broadcast ds_read_b128
            f32x2 ccx = (f32x2){c.x, c.x};
            f32x2 ccy = (f32x2){c.y, c.y};
            f32x2 ccz = (f32x2){c.z, c.z};
            float bv = -1.0f; int bn = 0;
#pragma unroll
            for (int jj = 0; jj < 8; jj++) {
                f32x2 dx, dy, dz, xx, yy, zz, s01, s;
                asm("v_pk_add_f32 %0, %1, %2 neg_lo:[0,1] neg_hi:[0,1]" : "=v"(dx) : "v"(px2[jj]), "v"(ccx));
                asm("v_pk_add_f32 %0, %1, %2 neg_lo:[0,1] neg_hi:[0,1]" : "=v"(dy) : "v"(py2[jj]), "v"(ccy));
                asm("v_pk_add_f32 %0, %1, %2 neg_lo:[0,1] neg_hi:[0,1]" : "=v"(dz) : "v"(pz2[jj]), "v"(ccz));
                asm("v_pk_mul_f32 %0, %1, %1" : "=v"(xx) : "v"(dx));
                asm("v_pk_mul_f32 %0, %1, %1" : "=v"(yy) : "v"(dy));
                asm("v_pk_mul_f32 %0, %1, %1" : "=v"(zz) : "v"(dz));
                asm("v_pk_add_f32 %0, %1, %2" : "=v"(s01) : "v"(xx), "v"(yy));
                asm("v_pk_add_f32 %0, %1, %2" : "=v"(s)   : "v"(s01), "v"(zz));
                float d0 = fminf(dm2[jj].x, s.x);
                dm2[jj].x = d0;
                bn = (d0 > bv) ? (jj * 512 + tid) : bn;   // ascending n: ties -> smaller n
                bv = fmaxf(bv, d0);
                float d1 = fminf(dm2[jj].y, s.y);
                dm2[jj].y = d1;
                bn = (d1 > bv) ? (jj * 512 + 256 + tid) : bn;
                bv = fmaxf(bv, d1);
            }
            uint32_t bvb = __float_as_uint(bv);           // bv >= 0: bits order-isomorphic
            uint32_t m = wave_umax32_dpp(bvb);
            unsigned long long mask = __ballot(bvb == m);
            int n_sel;
            if (__popcll(mask) == 1) {
                n_sel = __builtin_amdgcn_readlane(bn, (int)(__ffsll((unsigned long long)mask) - 1));
            } else {                                      // rare: d-tie across lanes -> min n
                uint32_t cand = (bvb == m) ? (uint32_t)bn : 0xFFFFFFFFu;
                n_sel = (int)~wave_umax32_dpp(~cand);
            }
            int par = t & 1;
            if ((tid & 63) == 0)
                kbufp[par * 4 + (tid >> 6)] =
                    ((unsigned long long)m << 32) | (unsigned)(NN - 1 - n_sel);
            __syncthreads();
            const ulonglong2* kp = (const ulonglong2*)(kbufp + par * 4);
            ulonglong2 k0 = kp[0], k1 = kp[1];
            unsigned long long mm = umax64(umax64(k0.x, k0.y), umax64(k1.x, k1.y));
            far = NN - 1 - (int)(unsigned)(mm & 0xFFFFFFFFull);
            if (tid == 0) {
                farr[t + 1] = far;
                __hip_atomic_store(&pub[t + 1], 0x10000u | (uint32_t)far,
                                   __ATOMIC_RELAXED, __HIP_MEMORY_SCOPE_AGENT);
            }
        }
        __syncthreads();
        float* nxb = out + (size_t)b * NP * 3;            // new_xyz output
        for (int t = tid; t < NP; t += FPS_T) {
            float4 p = sxyz[farr[t]];
            nxb[t * 3 + 0] = p.x;
            nxb[t * 3 + 1] = p.y;
            nxb[t * 3 + 2] = p.z;
        }
        return;
    }

    // ================= worker: knn + mlp per wave-task, no block barriers =================
    int wave = tid >> 6, lane = tid & 63;
    int l15  = lane & 15, quad = lane >> 4;
    int wv   = (blockIdx.x - BB) * 4 + wave;
    uint32_t* keys = (uint32_t*)smem + wave * NN;         // 16 KB per wave
    short* mG  = (short*)keys;                            // mlp G / h2 (32x96)
    short* mh1 = mG + 32 * 96;                            // mlp h1 (32x72)
    float* out_np = out + (size_t)BB * NP * 3;            // new_points output

    float b1v[4], b2v[4], b3v[8];
#pragma unroll
    for (int i = 0; i < 4; i++) b1v[i] = b1[l15 + 16 * i];
#pragma unroll
    for (int i = 0; i < 4; i++) b2v[i] = b2[l15 + 16 * i];
#pragma unroll
    for (int i = 0; i < 8; i++) b3v[i] = b3[l15 + 16 * i];

    for (int task = wv; task < BB * NP; task += NWAVES) {
        int s = task >> 4, b = task & (BB - 1);           // s-major: follow the fps frontier
        const float* xb = xyz + (size_t)b * NN * 3;
        // ---- spin for centroid s (self-contained payload: index) ----
        uint32_t v;
        for (;;) {
            v = __hip_atomic_load(&centpub[b * NP + s], __ATOMIC_RELAXED,
                                  __HIP_MEMORY_SCOPE_AGENT);
            if ((v >> 16) == 1u) break;
            __builtin_amdgcn_s_sleep(2);
        }
        int fr = (int)(v & 0xFFFFu);
        float cx = xb[fr * 3 + 0], cy = xb[fr * 3 + 1], cz = xb[fr * 3 + 2];
        float sn = sq3_exact(cx, cy, cz);

        asm volatile("" ::: "memory");                    // order LDS reuse across tasks
        // ---- knn: exact top-32 (R6 algorithm, indices kept in registers) ----
        uint32_t gv[8];
#pragma unroll
        for (int g = 0; g < 8; g++) gv[g] = 0;
#pragma unroll
        for (int j = 0; j < 64; j++) {
            int n = j * 64 + lane;
            float x = xb[n * 3 + 0], y = xb[n * 3 + 1], z = xb[n * 3 + 2];
            float sx = sq3_exact(x, y, z);
            float dt = dot3_exact(cx, cy, cz, x, y, z);
            float d2 = d2_exact(sn, sx, dt);
            uint32_t ck = ~f32_sortable(d2);
            keys[j * 64 + lane] = ck;
            gv[j >> 3] = umax32(gv[j >> 3], ck);
        }
        uint32_t best = 0;
#pragma unroll
        for (int g = 0; g < 8; g++) best = umax32(best, gv[g]);

        uint32_t myidx = 0;                               // lane r (r<32) keeps idx[r]
        for (int r = 0; r < KK; r++) {
            uint32_t m = wave_umax32_dpp(best);
            unsigned long long mask = __ballot(best == m);
            bool cand = (best == m);
            uint32_t myn = 0xFFFFFFFFu;
            int gsel = 7, jl = 7;
            uint32_t grp[8];
            if (cand) {
#pragma unroll
                for (int g = 6; g >= 0; g--) if (gv[g] == m) gsel = g;
#pragma unroll
                for (int q = 0; q < 8; q++) grp[q] = keys[(gsel * 8 + q) * 64 + lane];
#pragma unroll
                for (int q = 6; q >= 0; q--) if (grp[q] == m) jl = q;
                myn = (uint32_t)((gsel * 8 + jl) * 64 + lane);
            }
            uint32_t n_sel;
            if (__popcll(mask) > 1) {                     // rare: d2-tie -> min n
                n_sel = ~wave_umax32_dpp(~myn);
            } else {
                n_sel = (uint32_t)__builtin_amdgcn_readlane((int)myn,
                            (int)(__ffsll((unsigned long long)mask) - 1));
            }
            if (lane == r) myidx = n_sel;
            if (cand && myn == n_sel) {                   // owner: remove + rebuild
                keys[(gsel * 8 + jl) * 64 + lane] = 0;
#pragma unroll
                for (int q = 0; q < 8; q++) grp[q] = (q == jl) ? 0u : grp[q];
                uint32_t nv = 0;
#pragma unroll
                for (int q = 0; q < 8; q++) nv = umax32(nv, grp[q]);
#pragma unroll
                for (int g = 0; g < 8; g++) gv[g] = (g == gsel) ? nv : gv[g];
                best = 0;
#pragma unroll
                for (int g = 0; g < 8; g++) best = umax32(best, gv[g]);
            }
        }
        asm volatile("" ::: "memory");                    // keys dead; mlp overlays LDS

        // ---- mlp: gather + 3x MFMA layers + maxpool (R7 body, idx via shfl) ----
        {   // gather: 32 neighbors -> G rows (2 lanes per row)
            int rr = lane & 31, h = lane >> 5;
            int n = __shfl((int)myidx, rr);
            const short8* prow = (const short8*)(ptsT + ((size_t)b * NN + n) * CP);
            short8 c0 = prow[h * 4 + 0], c1 = prow[h * 4 + 1];
            short8 c2 = prow[h * 4 + 2], c3 = prow[h * 4 + 3];
            short8* gdst = (short8*)&mG[rr * 96];
            gdst[h * 4 + 0] = c0; gdst[h * 4 + 1] = c1;
            gdst[h * 4 + 2] = c2; gdst[h * 4 + 3] = c3;
            short8 z8 = {0, 0, 0, 0, 0, 0, 0, 0};
            if (h == 0) {
                const float* xp = xyz + ((size_t)b * NN + n) * 3;
                short8 vx = z8;
                vx[0] = (short)bf16_bits(xp[0]);
                vx[1] = (short)bf16_bits(xp[1]);
                vx[2] = (short)bf16_bits(xp[2]);
                gdst[8] = vx; gdst[9] = z8;
            } else {
                gdst[10] = z8; gdst[11] = z8;
            }
        }
        {   // layer 1: G(32x96) x W1p^T -> h1(32x64)
            floatx4 acc[2][4];
#pragma unroll
            for (int mt = 0; mt < 2; mt++)
#pragma unroll
                for (int nt = 0; nt < 4; nt++) acc[mt][nt] = (floatx4)0.0f;
#pragma unroll
            for (int kt = 0; kt < 3; kt++) {
                short8 a0 = *(const short8*)&mG[(l15) * 96 + kt * 32 + quad * 8];
                short8 a1 = *(const short8*)&mG[(l15 + 16) * 96 + kt * 32 + quad * 8];
#pragma unroll
                for (int nt = 0; nt < 4; nt++) {
                    short8 bf = *(const short8*)&w1p[(l15 + 16 * nt) * 96 + kt * 32 + quad * 8];
                    acc[0][nt] = __builtin_amdgcn_mfma_f32_16x16x32_bf16(a0, bf, acc[0][nt], 0, 0, 0);
                    acc[1][nt] = __builtin_amdgcn_mfma_f32_16x16x32_bf16(a1, bf, acc[1][nt], 0, 0, 0);
                }
            }
#pragma unroll
            for (int mt = 0; mt < 2; mt++)
#pragma unroll
                for (int nt = 0; nt < 4; nt++)
#pragma unroll
                    for (int r = 0; r < 4; r++) {
                        float vv = fmaxf(acc[mt][nt][r] + b1v[nt], 0.0f);
                        mh1[(quad * 4 + r + 16 * mt) * 72 + l15 + 16 * nt] = (short)bf16_bits(vv);
                    }
        }
        asm volatile("" ::: "memory");                    // h2 overlays dead G
        {   // layer 2: h1(32x64) x W2^T -> h2(32x64)
            floatx4 acc[2][4];
#pragma unroll
            for (int mt = 0; mt < 2; mt++)
#pragma unroll
                for (int nt = 0; nt < 4; nt++) acc[mt][nt] = (floatx4)0.0f;
#pragma unroll
            for (int kt = 0; kt < 2; kt++) {
                short8 a0 = *(const short8*)&mh1[(l15) * 72 + kt * 32 + quad * 8];
                short8 a1 = *(const short8*)&mh1[(l15 + 16) * 72 + kt * 32 + quad * 8];
#pragma unroll
                for (int nt = 0; nt < 4; nt++) {
                    short8 bf = *(const short8*)&w2p[(l15 + 16 * nt) * 64 + kt * 32 + quad * 8];
                    acc[0][nt] = __builtin_amdgcn_mfma_f32_16x16x32_bf16(a0, bf, acc[0][nt], 0, 0, 0);
                    acc[1][nt] = __builtin_amdgcn_mfma_f32_16x16x32_bf16(a1, bf, acc[1][nt], 0, 0, 0);
                }
            }
#pragma unroll
            for (int mt = 0; mt < 2; mt++)
#pragma unroll
                for (int nt = 0; nt < 4; nt++)
#pragma unroll
                    for (int r = 0; r < 4; r++) {
                        float vv = fmaxf(acc[mt][nt][r] + b2v[nt], 0.0f);
                        mG[(quad * 4 + r + 16 * mt) * 72 + l15 + 16 * nt] = (short)bf16_bits(vv);
                    }
        }
        {   // layer 3: h2(32x64) x W3^T -> (32x128), fused maxpool over 32 pts
            floatx4 acc[2][8];
#pragma unroll
            for (int mt = 0; mt < 2; mt++)
#pragma unroll
                for (int nt = 0; nt < 8; nt++) acc[mt][nt] = (floatx4)0.0f;
#pragma unroll
            for (int kt = 0; kt < 2; kt++) {
                short8 a0 = *(const short8*)&mG[(l15) * 72 + kt * 32 + quad * 8];
                short8 a1 = *(const short8*)&mG[(l15 + 16) * 72 + kt * 32 + quad * 8];
#pragma unroll
                for (int nt = 0; nt < 8; nt++) {
                    short8 bf = *(const short8*)&w3p[(l15 + 16 * nt) * 64 + kt * 32 + quad * 8];
                    acc[0][nt] = __builtin_amdgcn_mfma_f32_16x16x32_bf16(a0, bf, acc[0][nt], 0, 0, 0);
                    acc[1][nt] = __builtin_amdgcn_mfma_f32_16x16x32_bf16(a1, bf, acc[1][nt], 0, 0, 0);
                }
            }
#pragma unroll
            for (int nt = 0; nt < 8; nt++) {
                float m = acc[0][nt][0];
#pragma unroll
                for (int r = 1; r < 4; r++) m = fmaxf(m, acc[0][nt][r]);
#pragma unroll
                for (int r = 0; r < 4; r++) m = fmaxf(m, acc[1][nt][r]);
                m = fmaxf(m, __shfl_xor(m, 16));
                m = fmaxf(m, __shfl_xor(m, 32));
                m = fmaxf(m + b3v[nt], 0.0f);
                if (lane < 16)
                    out_np[((size_t)b * H3 + l15 + 16 * nt) * NP + s] = m;
            }
        }
    }
}

extern "C" void kernel_launch(void* const* d_in, const int* in_sizes, int n_in,
                              void* d_out, int out_size, void* d_ws, size_t ws_size,
                              hipStream_t stream) {
    (void)in_sizes; (void)n_in; (void)out_size; (void)ws_size;
    const float* xyz = (const float*)d_in[0];
    const float* pts = (const float*)d_in[1];
    const float* W1  = (const float*)d_in[2];
    const float* b1  = (const float*)d_in[3];
    const float* W2  = (const float*)d_in[4];
    const float* b2  = (const float*)d_in[5];
    const float* W3  = (const float*)d_in[6];
    const float* b3  = (const float*)d_in[7];

    float* out = (float*)d_out;                 // new_xyz (B,NP,3) then new_points (B,128,NP)

    char* ws = (char*)d_ws;
    __hip_bfloat16* ptsT = (__hip_bfloat16*)ws;                 // 8 MB
    uint32_t* centpub = (uint32_t*)(ws + 8388608);              // 64 KB
    short* w1p = (short*)(ws + 9437184);
    short* w2p = w1p + 64 * 96;
    short* w3p = w2p + 64 * 64;

    transpose_pts<<<dim3(NN / 64, BB), 256, 0, stream>>>(pts, ptsT);
    prep_weights <<<64, 256, 0, stream>>>(W1, W2, W3, w1p, w2p, w3p, centpub);
    fused_kernel <<<NGRID, 256, 0, stream>>>(xyz, ptsT, w1p, w2p, w3p,
                                             b1, b2, b3, centpub, out);
}

// Round 10
// 747.870 us; speedup vs baseline: 3.1175x; 1.0191x over previous
//
#include <hip/hip_runtime.h>
#include <hip/hip_bf16.h>
#include <stdint.h>
#include <string.h>

// Problem constants (fixed by setup_inputs).
#define BB   16
#define NN   4096
#define NP   1024
#define KK   32
#define CP   64
#define CIN  67    // 3 + 64
#define H3   128

#define FPS_T   256
#define NWORKB  240                 // worker blocks
#define NGRID   (BB + NWORKB)       // 256 blocks x 1 block/CU -> all co-resident
#define NWAVES  (NWORKB * 4)        // 960 worker waves for 16384 tasks
#define SMEM_BYTES 81984            // > 80 KB => exactly 1 block/CU (160 KB pool)

typedef __attribute__((ext_vector_type(8))) short short8;
typedef __attribute__((ext_vector_type(4))) float floatx4;
typedef __attribute__((ext_vector_type(2))) float f32x2;

// ---------- exact-rounding helpers (match numpy op-by-op; no fma contraction) ----------
__device__ __forceinline__ float sq3_exact(float x, float y, float z) {
#pragma clang fp contract(off)
    float a = x * x;
    float b = y * y;
    float c = z * z;
    return (a + b) + c;
}
__device__ __forceinline__ float dot3_exact(float ax, float ay, float az,
                                            float bx, float by, float bz) {
#pragma clang fp contract(off)
    float a = ax * bx;
    float b = ay * by;
    float c = az * bz;
    return (a + b) + c;
}
__device__ __forceinline__ float d2_exact(float sn, float sx, float dt) {
#pragma clang fp contract(off)
    return (sn + sx) - 2.0f * dt;
}
__device__ __forceinline__ uint32_t f32_sortable(float f) {
    uint32_t u = __float_as_uint(f);
    return u ^ ((uint32_t)((int32_t)u >> 31) | 0x80000000u);
}
__device__ __forceinline__ unsigned long long umax64(unsigned long long a, unsigned long long b) {
    return a > b ? a : b;
}
__device__ __forceinline__ uint32_t umax32(uint32_t a, uint32_t b) { return a > b ? a : b; }
__device__ __forceinline__ unsigned short bf16_bits(float f) {
    __hip_bfloat16 h = __float2bfloat16(f);
    unsigned short us;
    __builtin_memcpy(&us, &h, 2);
    return us;
}

// ---------- DPP wave64 u32-max reduce (VALU pipe; bound_ctrl=1 -> identity 0) ----------
template <int CTRL>
__device__ __forceinline__ uint32_t dpp_umax32_step(uint32_t k) {
    uint32_t o = (uint32_t)__builtin_amdgcn_update_dpp(0, (int)k, CTRL, 0xf, 0xf, true);
    return k > o ? k : o;
}
__device__ __forceinline__ uint32_t wave_umax32_dpp(uint32_t k) {
    k = dpp_umax32_step<0x111>(k);   // row_shr:1
    k = dpp_umax32_step<0x112>(k);   // row_shr:2
    k = dpp_umax32_step<0x114>(k);   // row_shr:4
    k = dpp_umax32_step<0x118>(k);   // row_shr:8
    k = dpp_umax32_step<0x142>(k);   // row_bcast:15
    k = dpp_umax32_step<0x143>(k);   // row_bcast:31
    return (uint32_t)__builtin_amdgcn_readlane((int)k, 63);
}

// ---------- prep: transpose points + weights->bf16 + zero publish flags (ONE launch) ----------
// blocks 0..1023: transpose tile (b = blk>>6, n0 = (blk&63)*64).
// blocks 1024..1039: centpub zero (required: harness only re-poisons d_ws before
// TIMED launches, so the ready flags MUST be cleared by a kernel ordered before
// fused_kernel on the stream) + bf16 weight prep (channel-reordered + padded).
__global__ void __launch_bounds__(256) prep_all(const float* __restrict__ pts,
                                                const float* __restrict__ W1,
                                                const float* __restrict__ W2,
                                                const float* __restrict__ W3,
                                                __hip_bfloat16* __restrict__ ptsT,
                                                short* __restrict__ w1p,
                                                short* __restrict__ w2p,
                                                short* __restrict__ w3p,
                                                uint32_t* __restrict__ centpub) {
    if (blockIdx.x < 1024) {
        __shared__ float tile[64][65];
        int b  = blockIdx.x >> 6;
        int n0 = (blockIdx.x & 63) * 64;
        int tx = threadIdx.x & 63, ty = threadIdx.x >> 6;   // 64 x 4
        const float* src = pts + (size_t)b * CP * NN;
        for (int c = ty; c < 64; c += 4)
            tile[c][tx] = src[c * NN + n0 + tx];
        __syncthreads();
        __hip_bfloat16* dst = ptsT + ((size_t)b * NN + n0) * CP;
        for (int nn2 = ty; nn2 < 64; nn2 += 4)
            dst[nn2 * CP + tx] = __float2bfloat16(tile[tx][nn2]);
        return;
    }
    int tid = (blockIdx.x - 1024) * 256 + threadIdx.x;
    int tot = 16 * 256;
    for (int i = tid; i < BB * NP; i += tot) centpub[i] = 0u;   // not-ready
    for (int i = tid; i < 64 * 96; i += tot) {
        int o = i / 96, c = i % 96;
        float v = (c < 64) ? W1[o * CIN + 3 + c] : ((c < 67) ? W1[o * CIN + (c - 64)] : 0.0f);
        w1p[i] = (short)bf16_bits(v);
    }
    for (int i = tid; i < 64 * 64; i += tot)  w2p[i] = (short)bf16_bits(W2[i]);
    for (int i = tid; i < 128 * 64; i += tot) w3p[i] = (short)bf16_bits(W3[i]);
}

// ---------- fused kernel: 16 FPS producer blocks + 240 knn+mlp worker blocks ----------
// SMEM_BYTES=81984 > 80KB => exactly 1 block/CU => 256 blocks all co-resident =>
// spin-wait cannot deadlock AND fps blocks own their CU exclusively (R9's 2-block/CU
// layout put a worker block on every fps CU; shared LDS pipe cost ~+90cyc/iter).
// Protocol: fps publishes centroid s as ONE relaxed agent-scope atomic u32
// (0x10000 | far). Payload is self-contained (consumer reads coords from the
// immutable xyz input). centpub pre-zeroed by prep_all => hi16==1 unambiguous.
__global__ void __launch_bounds__(256, 2)
fused_kernel(const float* __restrict__ xyz,
             const __hip_bfloat16* __restrict__ ptsT,
             const short* __restrict__ w1p,
             const short* __restrict__ w2p,
             const short* __restrict__ w3p,
             const float* __restrict__ b1,
             const float* __restrict__ b2,
             const float* __restrict__ b3,
             uint32_t* __restrict__ centpub,
             float* __restrict__ out) {
    __shared__ __attribute__((aligned(16))) char smem[SMEM_BYTES];
    int tid = threadIdx.x;

    if (blockIdx.x < BB) {
        // ================= FPS producer (R7 body + per-iter publish) =================
        asm volatile("s_setprio 3");            // win SIMD issue vs anything co-resident
        float4* sxyz = (float4*)smem;                                   // 64 KB
        int*    farr = (int*)(smem + 65536);                            // 4 KB
        unsigned long long* kbufp = (unsigned long long*)(smem + 69632);// 64 B
        int b = blockIdx.x;
        uint32_t* pub = centpub + b * NP;
        const float* xb = xyz + (size_t)b * NN * 3;
        if (tid == 0)
            __hip_atomic_store(&pub[0], 0x10000u, __ATOMIC_RELAXED, __HIP_MEMORY_SCOPE_AGENT);
        f32x2 px2[8], py2[8], pz2[8], dm2[8];
#pragma unroll
        for (int jj = 0; jj < 8; jj++) {
            int n0 = jj * 512 + tid;
            int n1 = n0 + 256;
            float x0 = xb[n0 * 3 + 0], y0 = xb[n0 * 3 + 1], z0 = xb[n0 * 3 + 2];
            float x1 = xb[n1 * 3 + 0], y1 = xb[n1 * 3 + 1], z1 = xb[n1 * 3 + 2];
            px2[jj] = (f32x2){x0, x1}; py2[jj] = (f32x2){y0, y1}; pz2[jj] = (f32x2){z0, z1};
            sxyz[n0] = make_float4(x0, y0, z0, 0.0f);
            sxyz[n1] = make_float4(x1, y1, z1, 0.0f);
            dm2[jj] = (f32x2){1e10f, 1e10f};              // matches 10000000000.0 init
        }
#pragma unroll
        for (int jj = 0; jj < 8; jj++) {                  // pin to VGPRs: no LDS remat
            asm volatile("" : "+v"(px2[jj]), "+v"(py2[jj]), "+v"(pz2[jj]));
        }
        if (tid == 0) farr[0] = 0;                        // cents[0] = 0
        __syncthreads();
        int far = 0;
        for (int t = 0; t < NP - 1; t++) {
            float4 c = sxyz[far];                         // broadcast ds_read_b128
            f32x2 ccx = (f32x2){c.x, c.x};
            f32x2 ccy = (f32x2){c.y, c.y};
            f32x2 ccz = (f32x2){c.z, c.z};
            float bv = -1.0f; int bn = 0;
#pragma unroll
            for (int jj = 0; jj < 8; jj++) {
                f32x2 dx, dy, dz, xx, yy, zz, s01, s;
                asm("v_pk_add_f32 %0, %1, %2 neg_lo:[0,1] neg_hi:[0,1]" : "=v"(dx) : "v"(px2[jj]), "v"(ccx));
                asm("v_pk_add_f32 %0, %1, %2 neg_lo:[0,1] neg_hi:[0,1]" : "=v"(dy) : "v"(py2[jj]), "v"(ccy));
                asm("v_pk_add_f32 %0, %1, %2 neg_lo:[0,1] neg_hi:[0,1]" : "=v"(dz) : "v"(pz2[jj]), "v"(ccz));
                asm("v_pk_mul_f32 %0, %1, %1" : "=v"(xx) : "v"(dx));
                asm("v_pk_mul_f32 %0, %1, %1" : "=v"(yy) : "v"(dy));
                asm("v_pk_mul_f32 %0, %1, %1" : "=v"(zz) : "v"(dz));
                asm("v_pk_add_f32 %0, %1, %2" : "=v"(s01) : "v"(xx), "v"(yy));
                asm("v_pk_add_f32 %0, %1, %2" : "=v"(s)   : "v"(s01), "v"(zz));
                float d0 = fminf(dm2[jj].x, s.x);
                dm2[jj].x = d0;
                bn = (d0 > bv) ? (jj * 512 + tid) : bn;   // ascending n: ties -> smaller n
                bv = fmaxf(bv, d0);
                float d1 = fminf(dm2[jj].y, s.y);
                dm2[jj].y = d1;
                bn = (d1 > bv) ? (jj * 512 + 256 + tid) : bn;
                bv = fmaxf(bv, d1);
            }
            uint32_t bvb = __float_as_uint(bv);           // bv >= 0: bits order-isomorphic
            uint32_t m = wave_umax32_dpp(bvb);
            unsigned long long mask = __ballot(bvb == m);
            int n_sel;
            if (__popcll(mask) == 1) {
                n_sel = __builtin_amdgcn_readlane(bn, (int)(__ffsll((unsigned long long)mask) - 1));
            } else {                                      // rare: d-tie across lanes -> min n
                uint32_t cand = (bvb == m) ? (uint32_t)bn : 0xFFFFFFFFu;
                n_sel = (int)~wave_umax32_dpp(~cand);
            }
            int par = t & 1;
            if ((tid & 63) == 0)
                kbufp[par * 4 + (tid >> 6)] =
                    ((unsigned long long)m << 32) | (unsigned)(NN - 1 - n_sel);
            __syncthreads();
            const ulonglong2* kp = (const ulonglong2*)(kbufp + par * 4);
            ulonglong2 k0 = kp[0], k1 = kp[1];
            unsigned long long mm = umax64(umax64(k0.x, k0.y), umax64(k1.x, k1.y));
            far = NN - 1 - (int)(unsigned)(mm & 0xFFFFFFFFull);
            if (tid == 0) {
                farr[t + 1] = far;
                __hip_atomic_store(&pub[t + 1], 0x10000u | (uint32_t)far,
                                   __ATOMIC_RELAXED, __HIP_MEMORY_SCOPE_AGENT);
            }
        }
        __syncthreads();
        float* nxb = out + (size_t)b * NP * 3;            // new_xyz output
        for (int t = tid; t < NP; t += FPS_T) {
            float4 p = sxyz[farr[t]];
            nxb[t * 3 + 0] = p.x;
            nxb[t * 3 + 1] = p.y;
            nxb[t * 3 + 2] = p.z;
        }
        return;
    }

    // ================= worker: knn + mlp per wave-task, no block barriers =================
    int wave = tid >> 6, lane = tid & 63;
    int l15  = lane & 15, quad = lane >> 4;
    int wv   = (blockIdx.x - BB) * 4 + wave;
    uint32_t* keys = (uint32_t*)smem + wave * NN;         // 16 KB per wave
    short* mG  = (short*)keys;                            // mlp G / h2 (32x96)
    short* mh1 = mG + 32 * 96;                            // mlp h1 (32x72)
    float* out_np = out + (size_t)BB * NP * 3;            // new_points output

    float b1v[4], b2v[4], b3v[8];
#pragma unroll
    for (int i = 0; i < 4; i++) b1v[i] = b1[l15 + 16 * i];
#pragma unroll
    for (int i = 0; i < 4; i++) b2v[i] = b2[l15 + 16 * i];
#pragma unroll
    for (int i = 0; i < 8; i++) b3v[i] = b3[l15 + 16 * i];

    for (int task = wv; task < BB * NP; task += NWAVES) {
        int s = task >> 4, b = task & (BB - 1);           // s-major: follow the fps frontier
        const float* xb = xyz + (size_t)b * NN * 3;
        // ---- spin for centroid s (self-contained payload: index) ----
        uint32_t v;
        for (;;) {
            v = __hip_atomic_load(&centpub[b * NP + s], __ATOMIC_RELAXED,
                                  __HIP_MEMORY_SCOPE_AGENT);
            if ((v >> 16) == 1u) break;
            __builtin_amdgcn_s_sleep(2);
        }
        int fr = (int)(v & 0xFFFFu);
        float cx = xb[fr * 3 + 0], cy = xb[fr * 3 + 1], cz = xb[fr * 3 + 2];
        float sn = sq3_exact(cx, cy, cz);

        asm volatile("" ::: "memory");                    // order LDS reuse across tasks
        // ---- knn: exact top-32 (R6 algorithm, indices kept in registers) ----
        uint32_t gv[8];
#pragma unroll
        for (int g = 0; g < 8; g++) gv[g] = 0;
#pragma unroll
        for (int j = 0; j < 64; j++) {
            int n = j * 64 + lane;
            float x = xb[n * 3 + 0], y = xb[n * 3 + 1], z = xb[n * 3 + 2];
            float sx = sq3_exact(x, y, z);
            float dt = dot3_exact(cx, cy, cz, x, y, z);
            float d2 = d2_exact(sn, sx, dt);
            uint32_t ck = ~f32_sortable(d2);
            keys[j * 64 + lane] = ck;
            gv[j >> 3] = umax32(gv[j >> 3], ck);
        }
        uint32_t best = 0;
#pragma unroll
        for (int g = 0; g < 8; g++) best = umax32(best, gv[g]);

        uint32_t myidx = 0;                               // lane r (r<32) keeps idx[r]
        for (int r = 0; r < KK; r++) {
            uint32_t m = wave_umax32_dpp(best);
            unsigned long long mask = __ballot(best == m);
            bool cand = (best == m);
            uint32_t myn = 0xFFFFFFFFu;
            int gsel = 7, jl = 7;
            uint32_t grp[8];
            if (cand) {
#pragma unroll
                for (int g = 6; g >= 0; g--) if (gv[g] == m) gsel = g;
#pragma unroll
                for (int q = 0; q < 8; q++) grp[q] = keys[(gsel * 8 + q) * 64 + lane];
#pragma unroll
                for (int q = 6; q >= 0; q--) if (grp[q] == m) jl = q;
                myn = (uint32_t)((gsel * 8 + jl) * 64 + lane);
            }
            uint32_t n_sel;
            if (__popcll(mask) > 1) {                     // rare: d2-tie -> min n
                n_sel = ~wave_umax32_dpp(~myn);
            } else {
                n_sel = (uint32_t)__builtin_amdgcn_readlane((int)myn,
                            (int)(__ffsll((unsigned long long)mask) - 1));
            }
            if (lane == r) myidx = n_sel;
            if (cand && myn == n_sel) {                   // owner: remove + rebuild
                keys[(gsel * 8 + jl) * 64 + lane] = 0;
#pragma unroll
                for (int q = 0; q < 8; q++) grp[q] = (q == jl) ? 0u : grp[q];
                uint32_t nv = 0;
#pragma unroll
                for (int q = 0; q < 8; q++) nv = umax32(nv, grp[q]);
#pragma unroll
                for (int g = 0; g < 8; g++) gv[g] = (g == gsel) ? nv : gv[g];
                best = 0;
#pragma unroll
                for (int g = 0; g < 8; g++) best = umax32(best, gv[g]);
            }
        }
        asm volatile("" ::: "memory");                    // keys dead; mlp overlays LDS

        // ---- mlp: gather + 3x MFMA layers + maxpool (idx via shfl) ----
        {   // gather: 32 neighbors -> G rows (2 lanes per row)
            int rr = lane & 31, h = lane >> 5;
            int n = __shfl((int)myidx, rr);
            const short8* prow = (const short8*)(ptsT + ((size_t)b * NN + n) * CP);
            short8 c0 = prow[h * 4 + 0], c1 = prow[h * 4 + 1];
            short8 c2 = prow[h * 4 + 2], c3 = prow[h * 4 + 3];
            short8* gdst = (short8*)&mG[rr * 96];
            gdst[h * 4 + 0] = c0; gdst[h * 4 + 1] = c1;
            gdst[h * 4 + 2] = c2; gdst[h * 4 + 3] = c3;
            short8 z8 = {0, 0, 0, 0, 0, 0, 0, 0};
            if (h == 0) {
                const float* xp = xyz + ((size_t)b * NN + n) * 3;
                short8 vx = z8;
                vx[0] = (short)bf16_bits(xp[0]);
                vx[1] = (short)bf16_bits(xp[1]);
                vx[2] = (short)bf16_bits(xp[2]);
                gdst[8] = vx; gdst[9] = z8;
            } else {
                gdst[10] = z8; gdst[11] = z8;
            }
        }
        {   // layer 1: G(32x96) x W1p^T -> h1(32x64)
            floatx4 acc[2][4];
#pragma unroll
            for (int mt = 0; mt < 2; mt++)
#pragma unroll
                for (int nt = 0; nt < 4; nt++) acc[mt][nt] = (floatx4)0.0f;
#pragma unroll
            for (int kt = 0; kt < 3; kt++) {
                short8 a0 = *(const short8*)&mG[(l15) * 96 + kt * 32 + quad * 8];
                short8 a1 = *(const short8*)&mG[(l15 + 16) * 96 + kt * 32 + quad * 8];
#pragma unroll
                for (int nt = 0; nt < 4; nt++) {
                    short8 bf = *(const short8*)&w1p[(l15 + 16 * nt) * 96 + kt * 32 + quad * 8];
                    acc[0][nt] = __builtin_amdgcn_mfma_f32_16x16x32_bf16(a0, bf, acc[0][nt], 0, 0, 0);
                    acc[1][nt] = __builtin_amdgcn_mfma_f32_16x16x32_bf16(a1, bf, acc[1][nt], 0, 0, 0);
                }
            }
#pragma unroll
            for (int mt = 0; mt < 2; mt++)
#pragma unroll
                for (int nt = 0; nt < 4; nt++)
#pragma unroll
                    for (int r = 0; r < 4; r++) {
                        float vv = fmaxf(acc[mt][nt][r] + b1v[nt], 0.0f);
                        mh1[(quad * 4 + r + 16 * mt) * 72 + l15 + 16 * nt] = (short)bf16_bits(vv);
                    }
        }
        asm volatile("" ::: "memory");                    // h2 overlays dead G
        {   // layer 2: h1(32x64) x W2^T -> h2(32x64)
            floatx4 acc[2][4];
#pragma unroll
            for (int mt = 0; mt < 2; mt++)
#pragma unroll
                for (int nt = 0; nt < 4; nt++) acc[mt][nt] = (floatx4)0.0f;
#pragma unroll
            for (int kt = 0; kt < 2; kt++) {
                short8 a0 = *(const short8*)&mh1[(l15) * 72 + kt * 32 + quad * 8];
                short8 a1 = *(const short8*)&mh1[(l15 + 16) * 72 + kt * 32 + quad * 8];
#pragma unroll
                for (int nt = 0; nt < 4; nt++) {
                    short8 bf = *(const short8*)&w2p[(l15 + 16 * nt) * 64 + kt * 32 + quad * 8];
                    acc[0][nt] = __builtin_amdgcn_mfma_f32_16x16x32_bf16(a0, bf, acc[0][nt], 0, 0, 0);
                    acc[1][nt] = __builtin_amdgcn_mfma_f32_16x16x32_bf16(a1, bf, acc[1][nt], 0, 0, 0);
                }
            }
#pragma unroll
            for (int mt = 0; mt < 2; mt++)
#pragma unroll
                for (int nt = 0; nt < 4; nt++)
#pragma unroll
                    for (int r = 0; r < 4; r++) {
                        float vv = fmaxf(acc[mt][nt][r] + b2v[nt], 0.0f);
                        mG[(quad * 4 + r + 16 * mt) * 72 + l15 + 16 * nt] = (short)bf16_bits(vv);
                    }
        }
        {   // layer 3: h2(32x64) x W3^T -> (32x128), fused maxpool over 32 pts
            floatx4 acc[2][8];
#pragma unroll
            for (int mt = 0; mt < 2; mt++)
#pragma unroll
                for (int nt = 0; nt < 8; nt++) acc[mt][nt] = (floatx4)0.0f;
#pragma unroll
            for (int kt = 0; kt < 2; kt++) {
                short8 a0 = *(const short8*)&mG[(l15) * 72 + kt * 32 + quad * 8];
                short8 a1 = *(const short8*)&mG[(l15 + 16) * 72 + kt * 32 + quad * 8];
#pragma unroll
                for (int nt = 0; nt < 8; nt++) {
                    short8 bf = *(const short8*)&w3p[(l15 + 16 * nt) * 64 + kt * 32 + quad * 8];
                    acc[0][nt] = __builtin_amdgcn_mfma_f32_16x16x32_bf16(a0, bf, acc[0][nt], 0, 0, 0);
                    acc[1][nt] = __builtin_amdgcn_mfma_f32_16x16x32_bf16(a1, bf, acc[1][nt], 0, 0, 0);
                }
            }
#pragma unroll
            for (int nt = 0; nt < 8; nt++) {
                float m = acc[0][nt][0];
#pragma unroll
                for (int r = 1; r < 4; r++) m = fmaxf(m, acc[0][nt][r]);
#pragma unroll
                for (int r = 0; r < 4; r++) m = fmaxf(m, acc[1][nt][r]);
                m = fmaxf(m, __shfl_xor(m, 16));
                m = fmaxf(m, __shfl_xor(m, 32));
                m = fmaxf(m + b3v[nt], 0.0f);
                if (lane < 16)
                    out_np[((size_t)b * H3 + l15 + 16 * nt) * NP + s] = m;
            }
        }
    }
}

extern "C" void kernel_launch(void* const* d_in, const int* in_sizes, int n_in,
                              void* d_out, int out_size, void* d_ws, size_t ws_size,
                              hipStream_t stream) {
    (void)in_sizes; (void)n_in; (void)out_size; (void)ws_size;
    const float* xyz = (const float*)d_in[0];
    const float* pts = (const float*)d_in[1];
    const float* W1  = (const float*)d_in[2];
    const float* b1  = (const float*)d_in[3];
    const float* W2  = (const float*)d_in[4];
    const float* b2  = (const float*)d_in[5];
    const float* W3  = (const float*)d_in[6];
    const float* b3  = (const float*)d_in[7];

    float* out = (float*)d_out;                 // new_xyz (B,NP,3) then new_points (B,128,NP)

    char* ws = (char*)d_ws;
    __hip_bfloat16* ptsT = (__hip_bfloat16*)ws;                 // 8 MB
    uint32_t* centpub = (uint32_t*)(ws + 8388608);              // 64 KB
    short* w1p = (short*)(ws + 9437184);
    short* w2p = w1p + 64 * 96;
    short* w3p = w2p + 64 * 64;

    prep_all    <<<1040, 256, 0, stream>>>(pts, W1, W2, W3, ptsT, w1p, w2p, w3p, centpub);
    fused_kernel<<<NGRID, 256, 0, stream>>>(xyz, ptsT, w1p, w2p, w3p,
                                            b1, b2, b3, centpub, out);
}